// Round 2
// baseline (235.905 us; speedup 1.0000x reference)
//
#include <hip/hip_runtime.h>
#include <hip/hip_fp16.h>
#include <cstdint>
#include <cstddef>

#define NHEAD 16
#define HDIM  64
#define HID   1024

using f16x8 = __attribute__((ext_vector_type(8))) _Float16;
using f32x4 = __attribute__((ext_vector_type(4))) float;

typedef const __attribute__((address_space(1))) unsigned int* gq_t;
typedef __attribute__((address_space(3))) unsigned int* lq_t;

// ---------------------------------------------------------------- converters
__global__ void cvt_f32_f16(const float* __restrict__ in, _Float16* __restrict__ out, int n8) {
    for (int i = blockIdx.x * blockDim.x + threadIdx.x; i < n8; i += gridDim.x * blockDim.x) {
        const float4* p = (const float4*)(in + (size_t)i * 8);
        float4 a = p[0], b = p[1];
        f16x8 o;
        o[0] = (_Float16)a.x; o[1] = (_Float16)a.y; o[2] = (_Float16)a.z; o[3] = (_Float16)a.w;
        o[4] = (_Float16)b.x; o[5] = (_Float16)b.y; o[6] = (_Float16)b.z; o[7] = (_Float16)b.w;
        *(f16x8*)(out + (size_t)i * 8) = o;
    }
}

// ------------------------------------------------------------------- GEMM
// C[M][N] = A[M][K] @ B[N][K]^T + bias[N]
// 256x256 tile, 8 waves (2x4), BK=64, 8-phase schedule (T2+T3+T4+T5):
// double-buffered LDS (128 KiB), counted vmcnt (never 0 in steady loop),
// XOR slot-swizzle (slot ^= row&7) -> measured 0 bank conflicts.
//
// LDS layout (f16 idx): [buf][mat A=0/B=1][half][128 rows][8 slots][8 f16]
//   A half mh: physical row rho = wm*64 + rloc  (global row wm*128+mh*64+rloc)
//   B half nh: physical row rho = wn*32 + rloc  (global col wn*64+nh*32+rloc)
// Swizzle: logical slot l of row rho stored at slot l ^ (rho&7).

#define VMCNT4  asm volatile("s_waitcnt vmcnt(4)" ::: "memory")
#define VMCNT0  asm volatile("s_waitcnt vmcnt(0)" ::: "memory")
#define LGKM0   asm volatile("s_waitcnt lgkmcnt(0)" ::: "memory")
#define BAR     __builtin_amdgcn_s_barrier()

#define READ_A(MH) { \
    const int base = buf * 32768 + (MH) * 8192 + (wm * 64) * 64; \
    _Pragma("unroll") for (int mi = 0; mi < 4; ++mi) { \
        const int rl = mi * 16 + l15; \
        _Pragma("unroll") for (int kk = 0; kk < 2; ++kk) { \
            const int slot = (kk * 4 + g) ^ l7; \
            a[mi][kk] = *(const f16x8*)&lds[base + rl * 64 + slot * 8]; \
        } } }

#define READ_B(NH, BREG) { \
    const int base = buf * 32768 + 16384 + (NH) * 8192 + (wn * 32) * 64; \
    _Pragma("unroll") for (int ni = 0; ni < 2; ++ni) { \
        const int rl = ni * 16 + l15; \
        _Pragma("unroll") for (int kk = 0; kk < 2; ++kk) { \
            const int slot = (kk * 4 + g) ^ l7; \
            BREG[ni][kk] = *(const f16x8*)&lds[base + rl * 64 + slot * 8]; \
        } } }

#define STAGE_A(T, MH) if ((T) < NT) { \
    const int bufS = (T) & 1; \
    _Pragma("unroll") for (int s = 0; s < 2; ++s) { \
        const int rho = s * 64 + wid * 8 + r_in; \
        const int r = ((rho >> 6) << 7) + (MH) * 64 + (rho & 63); \
        const int sg = s_l ^ r_in; \
        const _Float16* src = A + (size_t)(m0 + r) * K + (size_t)(T) * 64 + sg * 8; \
        _Float16* dst = (_Float16*)&lds[bufS * 32768 + (MH) * 8192 + (s * 64 + wid * 8) * 64]; \
        __builtin_amdgcn_global_load_lds((gq_t)(const void*)src, (lq_t)(void*)dst, 16, 0, 0); \
    } }

#define STAGE_B(T, NH) if ((T) < NT) { \
    const int bufS = (T) & 1; \
    _Pragma("unroll") for (int s = 0; s < 2; ++s) { \
        const int rho = s * 64 + wid * 8 + r_in; \
        const int r = ((rho >> 5) << 6) + (NH) * 32 + (rho & 31); \
        const int sg = s_l ^ r_in; \
        const _Float16* src = Bw + (size_t)(n0 + r) * K + (size_t)(T) * 64 + sg * 8; \
        _Float16* dst = (_Float16*)&lds[bufS * 32768 + 16384 + (NH) * 8192 + (s * 64 + wid * 8) * 64]; \
        __builtin_amdgcn_global_load_lds((gq_t)(const void*)src, (lq_t)(void*)dst, 16, 0, 0); \
    } }

#define MFMA_QUAD(MO, NO, BREG) \
    __builtin_amdgcn_s_setprio(1); \
    _Pragma("unroll") for (int mi = 0; mi < 4; ++mi) \
    _Pragma("unroll") for (int ni = 0; ni < 2; ++ni) \
    _Pragma("unroll") for (int kk = 0; kk < 2; ++kk) \
        acc[(MO) + mi][(NO) + ni] = __builtin_amdgcn_mfma_f32_16x16x32_f16( \
            a[mi][kk], BREG[ni][kk], acc[(MO) + mi][(NO) + ni], 0, 0, 0); \
    __builtin_amdgcn_s_setprio(0);

template <typename OutT>
__global__ __launch_bounds__(512, 2)
void gemm_bt8(const _Float16* __restrict__ A, const _Float16* __restrict__ Bw,
              const float* __restrict__ bias, OutT* __restrict__ C,
              int M, int N, int K)
{
    __shared__ _Float16 lds[65536];   // 128 KiB

    const int tid  = threadIdx.x;
    const int lane = tid & 63;
    const int wid  = tid >> 6;        // 0..7
    const int wm   = wid >> 2;        // 0..1  (128 rows each)
    const int wn   = wid & 3;         // 0..3  (64 cols each)
    const int m0   = blockIdx.y * 256;
    const int n0   = blockIdx.x * 256;
    const int NT   = K >> 6;          // K-tiles of 64

    const int l15  = lane & 15;
    const int l7   = lane & 7;
    const int g    = lane >> 4;       // k-group 0..3
    const int r_in = lane >> 3;       // staging row-in-chunk 0..7
    const int s_l  = lane & 7;        // staging slot

    f32x4 acc[8][4] = {};
    f16x8 a[4][2], b0[2][2], b1[2][2];

    // ---- prologue: tile0 all 4 halves + tile1 A0,B0 (12 loads/thread)
    STAGE_A(0, 0); STAGE_B(0, 0); STAGE_B(0, 1); STAGE_A(0, 1);
    STAGE_A(1, 0); STAGE_B(1, 0);
    VMCNT4;                           // tile0's 4 halves landed
    BAR;

    for (int t = 0; t < NT; ++t) {
        const int buf = t & 1;

        // ---- phase 0: quadrant (mh=0, nh=0); 12 ds_read
        READ_A(0); READ_B(0, b0);
        STAGE_B(t + 1, 1);
        BAR;
        LGKM0; __builtin_amdgcn_sched_barrier(0);
        MFMA_QUAD(0, 0, b0);
        BAR;

        // ---- phase 1: quadrant (mh=0, nh=1); 4 ds_read
        READ_B(1, b1);
        STAGE_A(t + 1, 1);
        BAR;
        LGKM0; __builtin_amdgcn_sched_barrier(0);
        MFMA_QUAD(0, 2, b1);
        BAR;

        // ---- phase 2: quadrant (mh=1, nh=0); 8 ds_read
        READ_A(1);
        STAGE_A(t + 2, 0);
        BAR;
        LGKM0; __builtin_amdgcn_sched_barrier(0);
        MFMA_QUAD(4, 0, b0);
        BAR;

        // ---- phase 3: quadrant (mh=1, nh=1); 0 ds_read
        STAGE_B(t + 2, 0);
        if (t == NT - 2) { VMCNT0; } else { VMCNT4; }
        BAR;
        MFMA_QUAD(4, 2, b1);
        BAR;
    }

    // ---- epilogue: bias + store. D: col = lane&15, row = (lane>>4)*4 + q
    #pragma unroll
    for (int an = 0; an < 4; ++an) {
        const int col = n0 + wn * 64 + (an >> 1) * 32 + (an & 1) * 16 + l15;
        const float bv = bias[col];
        #pragma unroll
        for (int am = 0; am < 8; ++am) {
            const int rowb = m0 + wm * 128 + (am >> 2) * 64 + (am & 3) * 16 + (lane >> 4) * 4;
            #pragma unroll
            for (int q = 0; q < 4; ++q) {
                const float val = acc[am][an][q] + bv;
                C[(size_t)(rowb + q) * N + col] = (OutT)val;
            }
        }
    }
}

// --------------------------------------------------------------- attention
// Per token: q,k,v in [16][64]; scores = (q*scale)@k^T / 8; softmax over t;
// out = attn @ v.  8 tokens/block, 128 threads: thread = (token, head-row h).
__global__ __launch_bounds__(128, 2)
void attn_kernel(const _Float16* __restrict__ qkv, const float* __restrict__ scale,
                 _Float16* __restrict__ out)
{
    __shared__ _Float16 kv[8][2048];   // per token: k[0..1024), v[1024..2048)
    __shared__ float sc[64];

    const int tid  = threadIdx.x;
    const int tok0 = blockIdx.x * 8;

    if (tid < 64) sc[tid] = scale[tid];

    #pragma unroll
    for (int it = 0; it < 16; ++it) {
        const int vid = tid + it * 128;
        const int tok = vid >> 8;
        const int ofs = (vid & 255) * 8;
        *(f16x8*)&kv[tok][ofs] =
            *(const f16x8*)&qkv[(size_t)(tok0 + tok) * 3072 + 1024 + ofs];
    }
    __syncthreads();

    const int tok = tid >> 4;
    const int h   = tid & 15;
    const size_t qbase = (size_t)(tok0 + tok) * 3072 + h * 64;

    float q[64];
    #pragma unroll
    for (int d0 = 0; d0 < 64; d0 += 8) {
        f16x8 qv = *(const f16x8*)&qkv[qbase + d0];
        #pragma unroll
        for (int j = 0; j < 8; ++j) q[d0 + j] = (float)qv[j] * sc[d0 + j];
    }

    float s[16];
    #pragma unroll
    for (int t = 0; t < 16; ++t) {
        float a = 0.f;
        #pragma unroll
        for (int d0 = 0; d0 < 64; d0 += 8) {
            f16x8 kvv = *(const f16x8*)&kv[tok][t * 64 + d0];
            #pragma unroll
            for (int j = 0; j < 8; ++j) a += q[d0 + j] * (float)kvv[j];
        }
        s[t] = a * 0.125f;
    }

    float mx = s[0];
    #pragma unroll
    for (int t = 1; t < 16; ++t) mx = fmaxf(mx, s[t]);
    float sum = 0.f;
    #pragma unroll
    for (int t = 0; t < 16; ++t) { s[t] = __expf(s[t] - mx); sum += s[t]; }
    const float inv = 1.f / sum;

    float o[64] = {};
    #pragma unroll
    for (int t = 0; t < 16; ++t) {
        const float a = s[t] * inv;
        #pragma unroll
        for (int d0 = 0; d0 < 64; d0 += 8) {
            f16x8 vv = *(const f16x8*)&kv[tok][1024 + t * 64 + d0];
            #pragma unroll
            for (int j = 0; j < 8; ++j) o[d0 + j] += a * (float)vv[j];
        }
    }

    #pragma unroll
    for (int d0 = 0; d0 < 64; d0 += 8) {
        f16x8 ov;
        #pragma unroll
        for (int j = 0; j < 8; ++j) ov[j] = (_Float16)o[d0 + j];
        *(f16x8*)&out[(size_t)(tok0 + tok) * 1024 + h * 64 + d0] = ov;
    }
}

// ----------------------------------------------------------------- launcher
extern "C" void kernel_launch(void* const* d_in, const int* in_sizes, int n_in,
                              void* d_out, int out_size, void* d_ws, size_t ws_size,
                              hipStream_t stream)
{
    const float* x     = (const float*)d_in[0];
    const float* Wq    = (const float*)d_in[1];
    const float* bq    = (const float*)d_in[2];
    const float* Wk    = (const float*)d_in[3];
    const float* bk    = (const float*)d_in[4];
    const float* Wv    = (const float*)d_in[5];
    const float* bv    = (const float*)d_in[6];
    const float* Wo    = (const float*)d_in[7];
    const float* bo    = (const float*)d_in[8];
    const float* scale = (const float*)d_in[9];
    float* out = (float*)d_out;

    const int M = in_sizes[0] / HID;   // 16384 tokens

    char* ws = (char*)d_ws;
    _Float16* x16    = (_Float16*)ws;
    _Float16* attn16 = x16;
    _Float16* wqkv16 = (_Float16*)(ws + (size_t)M * HID * 2);
    _Float16* wo16   = wqkv16 + (size_t)3 * HID * HID;
    float*    bqkv   = (float*)(wo16 + (size_t)HID * HID);
    _Float16* qkv16  = (_Float16*)((char*)bqkv + 3 * HID * 4);

    hipMemcpyAsync(bqkv,           bq, HID * 4, hipMemcpyDeviceToDevice, stream);
    hipMemcpyAsync(bqkv + HID,     bk, HID * 4, hipMemcpyDeviceToDevice, stream);
    hipMemcpyAsync(bqkv + 2 * HID, bv, HID * 4, hipMemcpyDeviceToDevice, stream);

    cvt_f32_f16<<<4096, 256, 0, stream>>>(x,  x16,                M * HID / 8);
    cvt_f32_f16<<<1024, 256, 0, stream>>>(Wq, wqkv16,             HID * HID / 8);
    cvt_f32_f16<<<1024, 256, 0, stream>>>(Wk, wqkv16 + HID * HID, HID * HID / 8);
    cvt_f32_f16<<<1024, 256, 0, stream>>>(Wv, wqkv16 + 2*HID*HID, HID * HID / 8);
    cvt_f32_f16<<<1024, 256, 0, stream>>>(Wo, wo16,               HID * HID / 8);

    // QKV GEMM: [M,1024] @ [3072,1024]^T -> qkv16 [M,3072] (f16)
    gemm_bt8<_Float16><<<dim3(3 * HID / 256, M / 256), 512, 0, stream>>>(
        x16, wqkv16, bqkv, qkv16, M, 3 * HID, HID);

    // per-token head-mix attention -> attn16 [M,1024] (f16)
    attn_kernel<<<M / 8, 128, 0, stream>>>(qkv16, scale, attn16);

    // output GEMM: [M,1024] @ [1024,1024]^T + bo -> out (f32)
    gemm_bt8<float><<<dim3(HID / 256, M / 256), 512, 0, stream>>>(
        attn16, wo16, bo, out, M, HID, HID);
}

// Round 3
// 224.356 us; speedup vs baseline: 1.0515x; 1.0515x over previous
//
#include <hip/hip_runtime.h>
#include <hip/hip_fp16.h>
#include <cstdint>
#include <cstddef>

#define NHEAD 16
#define HDIM  64
#define HID   1024

using f16x8 = __attribute__((ext_vector_type(8))) _Float16;
using f32x4 = __attribute__((ext_vector_type(4))) float;

typedef const __attribute__((address_space(1))) unsigned int* gq_t;
typedef __attribute__((address_space(3))) unsigned int* lq_t;

// ---------------------------------------------------------------- converters
__global__ void cvt_f32_f16(const float* __restrict__ in, _Float16* __restrict__ out, int n8) {
    for (int i = blockIdx.x * blockDim.x + threadIdx.x; i < n8; i += gridDim.x * blockDim.x) {
        const float4* p = (const float4*)(in + (size_t)i * 8);
        float4 a = p[0], b = p[1];
        f16x8 o;
        o[0] = (_Float16)a.x; o[1] = (_Float16)a.y; o[2] = (_Float16)a.z; o[3] = (_Float16)a.w;
        o[4] = (_Float16)b.x; o[5] = (_Float16)b.y; o[6] = (_Float16)b.z; o[7] = (_Float16)b.w;
        *(f16x8*)(out + (size_t)i * 8) = o;
    }
}

// all four 1024x1024 weights in one launch
__global__ void cvt_weights(const float* __restrict__ Wq, const float* __restrict__ Wk,
                            const float* __restrict__ Wv, const float* __restrict__ Wo,
                            _Float16* __restrict__ wqkv, _Float16* __restrict__ wo, int n8each) {
    for (int i = blockIdx.x * blockDim.x + threadIdx.x; i < 4 * n8each; i += gridDim.x * blockDim.x) {
        const int seg = i / n8each;
        const int off = i - seg * n8each;
        const float* src = (seg == 0) ? Wq : (seg == 1) ? Wk : (seg == 2) ? Wv : Wo;
        _Float16* dst = (seg < 3) ? (wqkv + (size_t)seg * HID * HID) : wo;
        const float4* p = (const float4*)(src + (size_t)off * 8);
        float4 a = p[0], b = p[1];
        f16x8 o;
        o[0] = (_Float16)a.x; o[1] = (_Float16)a.y; o[2] = (_Float16)a.z; o[3] = (_Float16)a.w;
        o[4] = (_Float16)b.x; o[5] = (_Float16)b.y; o[6] = (_Float16)b.z; o[7] = (_Float16)b.w;
        *(f16x8*)(dst + (size_t)off * 8) = o;
    }
}

// ------------------------------------------------------------------- GEMM
// C[M][N] = A[M][K] @ B[N][K]^T + bias[N]
// 256x256 tile, 8 waves (2x4), BK=64, 8-phase / 2-K-tiles-per-iter schedule
// (m201 template): static double-buffer alternation, counted vmcnt(6)
// (3 half-tiles in flight; vmcnt(0) only at T==NT-2), setprio around MFMA,
// XOR slot-swizzle (slot ^= row&7) -> 0 bank conflicts. NT must be even >= 4.

#define VMCNT6  asm volatile("s_waitcnt vmcnt(6)" ::: "memory")
#define VMCNT4  asm volatile("s_waitcnt vmcnt(4)" ::: "memory")
#define VMCNT0  asm volatile("s_waitcnt vmcnt(0)" ::: "memory")
#define LGKM0   asm volatile("s_waitcnt lgkmcnt(0)" ::: "memory")
#define LGKM8   asm volatile("s_waitcnt lgkmcnt(8)" ::: "memory")
#define BAR     __builtin_amdgcn_s_barrier()

#define READ_A(BUF, MH) { \
    const int base = (BUF) * 32768 + (MH) * 8192 + (wm * 64) * 64; \
    _Pragma("unroll") for (int mi = 0; mi < 4; ++mi) { \
        const int rl = mi * 16 + l15; \
        _Pragma("unroll") for (int kk = 0; kk < 2; ++kk) { \
            const int slot = (kk * 4 + g) ^ l7; \
            a[mi][kk] = *(const f16x8*)&lds[base + rl * 64 + slot * 8]; \
        } } }

#define READ_B(BUF, NH, BREG) { \
    const int base = (BUF) * 32768 + 16384 + (NH) * 8192 + (wn * 32) * 64; \
    _Pragma("unroll") for (int ni = 0; ni < 2; ++ni) { \
        const int rl = ni * 16 + l15; \
        _Pragma("unroll") for (int kk = 0; kk < 2; ++kk) { \
            const int slot = (kk * 4 + g) ^ l7; \
            BREG[ni][kk] = *(const f16x8*)&lds[base + rl * 64 + slot * 8]; \
        } } }

#define STAGE_A(T, MH) if ((T) < NT) { \
    const int bufS = (T) & 1; \
    _Pragma("unroll") for (int s = 0; s < 2; ++s) { \
        const int rho = s * 64 + wid * 8 + r_in; \
        const int r = ((rho >> 6) << 7) + (MH) * 64 + (rho & 63); \
        const int sg = s_l ^ r_in; \
        const _Float16* src = A + (size_t)(m0 + r) * K + (size_t)(T) * 64 + sg * 8; \
        _Float16* dst = (_Float16*)&lds[bufS * 32768 + (MH) * 8192 + (s * 64 + wid * 8) * 64]; \
        __builtin_amdgcn_global_load_lds((gq_t)(const void*)src, (lq_t)(void*)dst, 16, 0, 0); \
    } }

#define STAGE_B(T, NH) if ((T) < NT) { \
    const int bufS = (T) & 1; \
    _Pragma("unroll") for (int s = 0; s < 2; ++s) { \
        const int rho = s * 64 + wid * 8 + r_in; \
        const int r = ((rho >> 5) << 6) + (NH) * 32 + (rho & 31); \
        const int sg = s_l ^ r_in; \
        const _Float16* src = Bw + (size_t)(n0 + r) * K + (size_t)(T) * 64 + sg * 8; \
        _Float16* dst = (_Float16*)&lds[bufS * 32768 + 16384 + (NH) * 8192 + (s * 64 + wid * 8) * 64]; \
        __builtin_amdgcn_global_load_lds((gq_t)(const void*)src, (lq_t)(void*)dst, 16, 0, 0); \
    } }

#define MFMA_QUAD(MO, NO, BREG) \
    __builtin_amdgcn_s_setprio(1); \
    _Pragma("unroll") for (int mi = 0; mi < 4; ++mi) \
    _Pragma("unroll") for (int ni = 0; ni < 2; ++ni) \
    _Pragma("unroll") for (int kk = 0; kk < 2; ++kk) \
        acc[(MO) + mi][(NO) + ni] = __builtin_amdgcn_mfma_f32_16x16x32_f16( \
            a[mi][kk], BREG[ni][kk], acc[(MO) + mi][(NO) + ni], 0, 0, 0); \
    __builtin_amdgcn_s_setprio(0);

// one K-tile = 4 phases; BUF is a literal 0/1
#define TILE(T, BUF) { \
    /* phase 0: quadrant (0,0); 12 ds_read */ \
    READ_A(BUF, 0); READ_B(BUF, 0, b0); \
    STAGE_A((T) + 1, 1); \
    LGKM8; \
    BAR; LGKM0; \
    MFMA_QUAD(0, 0, b0); \
    BAR; \
    /* phase 1: quadrant (0,1); 4 ds_read */ \
    READ_B(BUF, 1, b1); \
    STAGE_A((T) + 2, 0); \
    BAR; LGKM0; \
    MFMA_QUAD(0, 2, b1); \
    BAR; \
    /* phase 2: quadrant (1,0); 8 ds_read */ \
    READ_A(BUF, 1); \
    STAGE_B((T) + 2, 0); \
    BAR; LGKM0; \
    MFMA_QUAD(4, 0, b0); \
    BAR; \
    /* phase 3: quadrant (1,1); 0 ds_read */ \
    STAGE_B((T) + 2, 1); \
    if ((T) == NT - 2) { VMCNT0; } else { VMCNT6; } \
    BAR; \
    MFMA_QUAD(4, 2, b1); \
    BAR; }

template <typename OutT>
__global__ __launch_bounds__(512, 2)
void gemm_bt8(const _Float16* __restrict__ A, const _Float16* __restrict__ Bw,
              const float* __restrict__ bias, OutT* __restrict__ C,
              int M, int N, int K)
{
    __shared__ _Float16 lds[65536];   // 128 KiB

    const int tid  = threadIdx.x;
    const int lane = tid & 63;
    const int wid  = tid >> 6;        // 0..7
    const int wm   = wid >> 2;        // 0..1  (128 rows each)
    const int wn   = wid & 3;         // 0..3  (64 cols each)
    const int m0   = blockIdx.y * 256;
    const int n0   = blockIdx.x * 256;
    const int NT   = K >> 6;          // K-tiles of 64 (even, >= 4)

    const int l15  = lane & 15;
    const int l7   = lane & 7;
    const int g    = lane >> 4;       // k-group 0..3
    const int r_in = lane >> 3;       // staging row-in-chunk 0..7
    const int s_l  = lane & 7;        // staging slot

    f32x4 acc[8][4] = {};
    f16x8 a[4][2], b0[2][2], b1[2][2];

    // ---- prologue: tile0's 4 halves, pace, then 3 halves of tile1
    STAGE_A(0, 0); STAGE_B(0, 0); STAGE_B(0, 1); STAGE_A(0, 1);
    VMCNT4;
    STAGE_A(1, 0); STAGE_B(1, 0); STAGE_B(1, 1);
    VMCNT6;                            // tile0 fully landed; 3 halves in flight
    BAR;

    for (int e = 0; e < NT; e += 2) {
        TILE(e, 0);
        TILE(e + 1, 1);
    }

    // ---- epilogue: bias + store. D: col = lane&15, row = (lane>>4)*4 + q
    #pragma unroll
    for (int an = 0; an < 4; ++an) {
        const int col = n0 + wn * 64 + (an >> 1) * 32 + (an & 1) * 16 + l15;
        const float bv = bias[col];
        #pragma unroll
        for (int am = 0; am < 8; ++am) {
            const int rowb = m0 + wm * 128 + (am >> 2) * 64 + (am & 3) * 16 + (lane >> 4) * 4;
            #pragma unroll
            for (int q = 0; q < 4; ++q) {
                const float val = acc[am][an][q] + bv;
                C[(size_t)(rowb + q) * N + col] = (OutT)val;
            }
        }
    }
}

// --------------------------------------------------------------- attention
__global__ __launch_bounds__(128, 2)
void attn_kernel(const _Float16* __restrict__ qkv, const float* __restrict__ scale,
                 _Float16* __restrict__ out)
{
    __shared__ _Float16 kv[8][2048];   // per token: k[0..1024), v[1024..2048)
    __shared__ float sc[64];

    const int tid  = threadIdx.x;
    const int tok0 = blockIdx.x * 8;

    if (tid < 64) sc[tid] = scale[tid];

    #pragma unroll
    for (int it = 0; it < 16; ++it) {
        const int vid = tid + it * 128;
        const int tok = vid >> 8;
        const int ofs = (vid & 255) * 8;
        *(f16x8*)&kv[tok][ofs] =
            *(const f16x8*)&qkv[(size_t)(tok0 + tok) * 3072 + 1024 + ofs];
    }
    __syncthreads();

    const int tok = tid >> 4;
    const int h   = tid & 15;
    const size_t qbase = (size_t)(tok0 + tok) * 3072 + h * 64;

    float q[64];
    #pragma unroll
    for (int d0 = 0; d0 < 64; d0 += 8) {
        f16x8 qv = *(const f16x8*)&qkv[qbase + d0];
        #pragma unroll
        for (int j = 0; j < 8; ++j) q[d0 + j] = (float)qv[j] * sc[d0 + j];
    }

    float s[16];
    #pragma unroll
    for (int t = 0; t < 16; ++t) {
        float acc = 0.f;
        #pragma unroll
        for (int d0 = 0; d0 < 64; d0 += 8) {
            f16x8 kvv = *(const f16x8*)&kv[tok][t * 64 + d0];
            #pragma unroll
            for (int j = 0; j < 8; ++j) acc += q[d0 + j] * (float)kvv[j];
        }
        s[t] = acc * 0.125f;
    }

    float mx = s[0];
    #pragma unroll
    for (int t = 1; t < 16; ++t) mx = fmaxf(mx, s[t]);
    float sum = 0.f;
    #pragma unroll
    for (int t = 0; t < 16; ++t) { s[t] = __expf(s[t] - mx); sum += s[t]; }
    const float inv = 1.f / sum;

    float o[64] = {};
    #pragma unroll
    for (int t = 0; t < 16; ++t) {
        const float aw = s[t] * inv;
        #pragma unroll
        for (int d0 = 0; d0 < 64; d0 += 8) {
            f16x8 vv = *(const f16x8*)&kv[tok][1024 + t * 64 + d0];
            #pragma unroll
            for (int j = 0; j < 8; ++j) o[d0 + j] += aw * (float)vv[j];
        }
    }

    #pragma unroll
    for (int d0 = 0; d0 < 64; d0 += 8) {
        f16x8 ov;
        #pragma unroll
        for (int j = 0; j < 8; ++j) ov[j] = (_Float16)o[d0 + j];
        *(f16x8*)&out[(size_t)(tok0 + tok) * 1024 + h * 64 + d0] = ov;
    }
}

// ----------------------------------------------------------------- launcher
extern "C" void kernel_launch(void* const* d_in, const int* in_sizes, int n_in,
                              void* d_out, int out_size, void* d_ws, size_t ws_size,
                              hipStream_t stream)
{
    const float* x     = (const float*)d_in[0];
    const float* Wq    = (const float*)d_in[1];
    const float* bq    = (const float*)d_in[2];
    const float* Wk    = (const float*)d_in[3];
    const float* bk    = (const float*)d_in[4];
    const float* Wv    = (const float*)d_in[5];
    const float* bv    = (const float*)d_in[6];
    const float* Wo    = (const float*)d_in[7];
    const float* bo    = (const float*)d_in[8];
    const float* scale = (const float*)d_in[9];
    float* out = (float*)d_out;

    const int M = in_sizes[0] / HID;   // 16384 tokens

    char* ws = (char*)d_ws;
    _Float16* x16    = (_Float16*)ws;
    _Float16* attn16 = x16;
    _Float16* wqkv16 = (_Float16*)(ws + (size_t)M * HID * 2);
    _Float16* wo16   = wqkv16 + (size_t)3 * HID * HID;
    float*    bqkv   = (float*)(wo16 + (size_t)HID * HID);
    _Float16* qkv16  = (_Float16*)((char*)bqkv + 3 * HID * 4);

    hipMemcpyAsync(bqkv,           bq, HID * 4, hipMemcpyDeviceToDevice, stream);
    hipMemcpyAsync(bqkv + HID,     bk, HID * 4, hipMemcpyDeviceToDevice, stream);
    hipMemcpyAsync(bqkv + 2 * HID, bv, HID * 4, hipMemcpyDeviceToDevice, stream);

    cvt_f32_f16<<<4096, 256, 0, stream>>>(x, x16, M * HID / 8);
    cvt_weights<<<2048, 256, 0, stream>>>(Wq, Wk, Wv, Wo, wqkv16, wo16, HID * HID / 8);

    // QKV GEMM: [M,1024] @ [3072,1024]^T -> qkv16 [M,3072] (f16)
    gemm_bt8<_Float16><<<dim3(3 * HID / 256, M / 256), 512, 0, stream>>>(
        x16, wqkv16, bqkv, qkv16, M, 3 * HID, HID);

    // per-token head-mix attention -> attn16 [M,1024] (f16)
    attn_kernel<<<M / 8, 128, 0, stream>>>(qkv16, scale, attn16);

    // output GEMM: [M,1024] @ [1024,1024]^T + bo -> out (f32)
    gemm_bt8<float><<<dim3(HID / 256, M / 256), 512, 0, stream>>>(
        attn16, wo16, bo, out, M, HID, HID);
}

// Round 4
// 215.605 us; speedup vs baseline: 1.0942x; 1.0406x over previous
//
#include <hip/hip_runtime.h>
#include <hip/hip_fp16.h>
#include <cstdint>
#include <cstddef>

#define NHEAD 16
#define HDIM  64
#define HID   1024

using f16x8 = __attribute__((ext_vector_type(8))) _Float16;
using f32x4 = __attribute__((ext_vector_type(4))) float;

typedef const __attribute__((address_space(1))) unsigned int* gq_t;
typedef __attribute__((address_space(3))) unsigned int* lq_t;

// ------------------------------------------------------- fused converter
// Converts x (M*HID f32) -> x16, Wq/Wk/Wv -> wqkv16, Wo -> wo16 (f16),
// and copies bq|bk|bv -> bqkv (f32) in a single launch.
__global__ void cvt_all(const float* __restrict__ x,
                        const float* __restrict__ Wq, const float* __restrict__ Wk,
                        const float* __restrict__ Wv, const float* __restrict__ Wo,
                        const float* __restrict__ bq, const float* __restrict__ bk,
                        const float* __restrict__ bv,
                        _Float16* __restrict__ x16, _Float16* __restrict__ wqkv,
                        _Float16* __restrict__ wo, float* __restrict__ bqkv,
                        int n8x, int n8w)
{
    const int n8tot = n8x + 4 * n8w;
    for (int i = blockIdx.x * blockDim.x + threadIdx.x; i < n8tot; i += gridDim.x * blockDim.x) {
        const float* src;
        _Float16* dst;
        size_t off;
        if (i < n8x) {
            src = x; dst = x16; off = (size_t)i;
        } else {
            const int j = i - n8x;
            const int seg = j / n8w;
            off = (size_t)(j - seg * n8w);
            src = (seg == 0) ? Wq : (seg == 1) ? Wk : (seg == 2) ? Wv : Wo;
            dst = (seg < 3) ? (wqkv + (size_t)seg * HID * HID) : wo;
        }
        const float4* p = (const float4*)(src + off * 8);
        float4 a = p[0], b = p[1];
        f16x8 o;
        o[0] = (_Float16)a.x; o[1] = (_Float16)a.y; o[2] = (_Float16)a.z; o[3] = (_Float16)a.w;
        o[4] = (_Float16)b.x; o[5] = (_Float16)b.y; o[6] = (_Float16)b.z; o[7] = (_Float16)b.w;
        *(f16x8*)(dst + off * 8) = o;
    }
    // biases: 3*1024 floats = 384 vec8 chunks
    const int bi = blockIdx.x * blockDim.x + threadIdx.x;
    if (bi < 384) {
        const int seg = bi >> 7;            // 0..2 (128 vec8 per bias)
        const int off = (bi & 127) * 8;
        const float* src = (seg == 0) ? bq : (seg == 1) ? bk : bv;
        const float4* p = (const float4*)(src + off);
        float4 a = p[0], b = p[1];
        float4* q = (float4*)(bqkv + seg * HID + off);
        q[0] = a; q[1] = b;
    }
}

// ------------------------------------------------------------------- GEMM
// C[M][N] = A[M][K] @ B[N][K]^T + bias[N]
// 128x128 tile, 4 waves (2x2), BK=64, global_load_lds staging,
// XOR slot-swizzle (slot ^= row&7) -> measured 0 bank conflicts.
template <typename OutT>
__global__ __launch_bounds__(256, 4)
void gemm_bt(const _Float16* __restrict__ A, const _Float16* __restrict__ Bw,
             const float* __restrict__ bias, OutT* __restrict__ C,
             int M, int N, int K)
{
    __shared__ _Float16 As[128 * 64];
    __shared__ _Float16 Bs[128 * 64];

    const int tid  = threadIdx.x;
    const int lane = tid & 63;
    const int wid  = tid >> 6;
    const int wm   = wid >> 1;   // 0..1
    const int wn   = wid & 1;    // 0..1
    const int m0   = blockIdx.y * 128;
    const int n0   = blockIdx.x * 128;

    f32x4 acc[4][4] = {};

    const int r_in  = lane >> 3;       // 0..7 row within wave's 8-row strip
    const int s_lds = lane & 7;        // 0..7 16B slot within row

    for (int k0 = 0; k0 < K; k0 += 64) {
        // ---- stage A,B tiles (128 rows x 64 f16 = 16 KiB each), 4 issues per matrix
        #pragma unroll
        for (int j = 0; j < 4; ++j) {
            const int rbase = j * 32 + wid * 8;       // wave-uniform
            const int r     = rbase + r_in;
            const int s_g   = s_lds ^ (r & 7);        // pre-swizzled global source
            const _Float16* ga = A  + (size_t)(m0 + r) * K + k0 + s_g * 8;
            const _Float16* gb = Bw + (size_t)(n0 + r) * K + k0 + s_g * 8;
            __builtin_amdgcn_global_load_lds((gq_t)(const void*)ga,
                                             (lq_t)(void*)(As + rbase * 64), 16, 0, 0);
            __builtin_amdgcn_global_load_lds((gq_t)(const void*)gb,
                                             (lq_t)(void*)(Bs + rbase * 64), 16, 0, 0);
        }
        __syncthreads();

        // ---- compute: 2 K-steps of 32, 16 MFMA each
        const int g = lane >> 4;              // k-group 0..3
        #pragma unroll
        for (int kk = 0; kk < 2; ++kk) {
            f16x8 af[4], bf[4];
            #pragma unroll
            for (int mi = 0; mi < 4; ++mi) {
                const int row  = wm * 64 + mi * 16 + (lane & 15);
                const int slot = (kk * 4 + g) ^ (row & 7);
                af[mi] = *(const f16x8*)&As[row * 64 + slot * 8];
            }
            #pragma unroll
            for (int ni = 0; ni < 4; ++ni) {
                const int row  = wn * 64 + ni * 16 + (lane & 15);
                const int slot = (kk * 4 + g) ^ (row & 7);
                bf[ni] = *(const f16x8*)&Bs[row * 64 + slot * 8];
            }
            #pragma unroll
            for (int mi = 0; mi < 4; ++mi)
                #pragma unroll
                for (int ni = 0; ni < 4; ++ni)
                    acc[mi][ni] = __builtin_amdgcn_mfma_f32_16x16x32_f16(
                        af[mi], bf[ni], acc[mi][ni], 0, 0, 0);
        }
        __syncthreads();
    }

    // ---- epilogue: bias + store. D: col = lane&15, row = (lane>>4)*4 + q
    #pragma unroll
    for (int ni = 0; ni < 4; ++ni) {
        const int col = n0 + wn * 64 + ni * 16 + (lane & 15);
        const float bv = bias[col];
        #pragma unroll
        for (int mi = 0; mi < 4; ++mi) {
            const int rowb = m0 + wm * 64 + mi * 16 + (lane >> 4) * 4;
            #pragma unroll
            for (int q = 0; q < 4; ++q) {
                const float val = acc[mi][ni][q] + bv;
                C[(size_t)(rowb + q) * N + col] = (OutT)val;
            }
        }
    }
}

// --------------------------------------------------------------- attention
// Per token: q,k,v in [16][64]; scores = (q*scale)@k^T / 8; softmax over t;
// out = attn @ v.  8 tokens/block, 128 threads: thread = (token, head-row h).
__global__ __launch_bounds__(128, 2)
void attn_kernel(const _Float16* __restrict__ qkv, const float* __restrict__ scale,
                 _Float16* __restrict__ out)
{
    __shared__ _Float16 kv[8][2048];   // per token: k[0..1024), v[1024..2048)
    __shared__ float sc[64];

    const int tid  = threadIdx.x;
    const int tok0 = blockIdx.x * 8;

    if (tid < 64) sc[tid] = scale[tid];

    #pragma unroll
    for (int it = 0; it < 16; ++it) {
        const int vid = tid + it * 128;
        const int tok = vid >> 8;
        const int ofs = (vid & 255) * 8;
        *(f16x8*)&kv[tok][ofs] =
            *(const f16x8*)&qkv[(size_t)(tok0 + tok) * 3072 + 1024 + ofs];
    }
    __syncthreads();

    const int tok = tid >> 4;
    const int h   = tid & 15;
    const size_t qbase = (size_t)(tok0 + tok) * 3072 + h * 64;

    float q[64];
    #pragma unroll
    for (int d0 = 0; d0 < 64; d0 += 8) {
        f16x8 qv = *(const f16x8*)&qkv[qbase + d0];
        #pragma unroll
        for (int j = 0; j < 8; ++j) q[d0 + j] = (float)qv[j] * sc[d0 + j];
    }

    float s[16];
    #pragma unroll
    for (int t = 0; t < 16; ++t) {
        float a = 0.f;
        #pragma unroll
        for (int d0 = 0; d0 < 64; d0 += 8) {
            f16x8 kvv = *(const f16x8*)&kv[tok][t * 64 + d0];
            #pragma unroll
            for (int j = 0; j < 8; ++j) a += q[d0 + j] * (float)kvv[j];
        }
        s[t] = a * 0.125f;
    }

    float mx = s[0];
    #pragma unroll
    for (int t = 1; t < 16; ++t) mx = fmaxf(mx, s[t]);
    float sum = 0.f;
    #pragma unroll
    for (int t = 0; t < 16; ++t) { s[t] = __expf(s[t] - mx); sum += s[t]; }
    const float inv = 1.f / sum;

    float o[64] = {};
    #pragma unroll
    for (int t = 0; t < 16; ++t) {
        const float a = s[t] * inv;
        #pragma unroll
        for (int d0 = 0; d0 < 64; d0 += 8) {
            f16x8 vv = *(const f16x8*)&kv[tok][1024 + t * 64 + d0];
            #pragma unroll
            for (int j = 0; j < 8; ++j) o[d0 + j] += a * (float)vv[j];
        }
    }

    #pragma unroll
    for (int d0 = 0; d0 < 64; d0 += 8) {
        f16x8 ov;
        #pragma unroll
        for (int j = 0; j < 8; ++j) ov[j] = (_Float16)o[d0 + j];
        *(f16x8*)&out[(size_t)(tok0 + tok) * 1024 + h * 64 + d0] = ov;
    }
}

// ----------------------------------------------------------------- launcher
extern "C" void kernel_launch(void* const* d_in, const int* in_sizes, int n_in,
                              void* d_out, int out_size, void* d_ws, size_t ws_size,
                              hipStream_t stream)
{
    const float* x     = (const float*)d_in[0];
    const float* Wq    = (const float*)d_in[1];
    const float* bq    = (const float*)d_in[2];
    const float* Wk    = (const float*)d_in[3];
    const float* bk    = (const float*)d_in[4];
    const float* Wv    = (const float*)d_in[5];
    const float* bv    = (const float*)d_in[6];
    const float* Wo    = (const float*)d_in[7];
    const float* bo    = (const float*)d_in[8];
    const float* scale = (const float*)d_in[9];
    float* out = (float*)d_out;

    const int M = in_sizes[0] / HID;   // 16384 tokens

    char* ws = (char*)d_ws;
    _Float16* x16    = (_Float16*)ws;
    _Float16* attn16 = x16;
    _Float16* wqkv16 = (_Float16*)(ws + (size_t)M * HID * 2);
    _Float16* wo16   = wqkv16 + (size_t)3 * HID * HID;
    float*    bqkv   = (float*)(wo16 + (size_t)HID * HID);
    _Float16* qkv16  = (_Float16*)((char*)bqkv + 3 * HID * 4);

    // fused conversions: x, Wq/Wk/Wv, Wo, biases — one launch
    cvt_all<<<4096, 256, 0, stream>>>(x, Wq, Wk, Wv, Wo, bq, bk, bv,
                                      x16, wqkv16, wo16, bqkv,
                                      M * HID / 8, HID * HID / 8);

    // QKV GEMM: [M,1024] @ [3072,1024]^T -> qkv16 [M,3072] (f16)
    gemm_bt<_Float16><<<dim3(3 * HID / 128, M / 128), 256, 0, stream>>>(
        x16, wqkv16, bqkv, qkv16, M, 3 * HID, HID);

    // per-token head-mix attention -> attn16 [M,1024] (f16)
    attn_kernel<<<M / 8, 128, 0, stream>>>(qkv16, scale, attn16);

    // output GEMM: [M,1024] @ [1024,1024]^T + bo -> out (f32)
    gemm_bt<float><<<dim3(HID / 128, M / 128), 256, 0, stream>>>(
        attn16, wo16, bo, out, M, HID, HID);
}